// Round 7
// baseline (1072.096 us; speedup 1.0000x reference)
//
#include <hip/hip_runtime.h>

#define C_GMS 0.0026f

// DPP wavefront shifts: full-rate VALU cross-lane, zero LDS latency.
// dppL = value of lane-1 (wf_shr:1, 0x138), lane 0 reads 0 (bound_ctrl)
// dppR = value of lane+1 (wf_shl:1, 0x130), lane 63 reads 0
__device__ __forceinline__ float dppL(float x) {
    return __int_as_float(__builtin_amdgcn_mov_dpp(__float_as_int(x), 0x138, 0xf, 0xf, true));
}
__device__ __forceinline__ float dppR(float x) {
    return __int_as_float(__builtin_amdgcn_mov_dpp(__float_as_int(x), 0x130, 0xf, 0xf, true));
}
__device__ __forceinline__ float med3f(float a, float b, float c) {
    return __builtin_amdgcn_fmed3f(a, b, c);   // exact median-of-3, 1 instr
}

// unit layout: [0,9216) scale0 | [,11776) scale1 | [,12544) scale2 | [,12800) scale3
#define N0 9216
#define N1 2560
#define N2 768
#define N3 256
#define NTOT 12800
#define NBLK (NTOT / 4)
#define PER_IMG 576u   // scale0 units per image (9 strips * 64 chunks)

// Rolling GMS core (verified exact R3-R6, absmax=0): one wave = 64-col strip,
// 8 output rows. median9 = med3(max3(col lows), med3(col meds), min3(col highs)).
// Returns lane-reduced partial sum (valid in lane 0).
template<class LoadFn, class PoolFn>
__device__ __forceinline__ float gms_core(int lane, int Hk, int R0, int iend, int c,
                                          int phalf, LoadFn loadrow2, PoolFn dopool)
{
    auto medrow = [&](float ga, float gb, float gc, float& m, float& rs) {
        float lo = fminf(fminf(ga, gb), gc);
        float me = med3f(ga, gb, gc);
        float hi = fmaxf(fmaxf(ga, gb), gc);
        float lmax = fmaxf(fmaxf(dppL(lo), lo), dppR(lo));
        float mid  = med3f(dppL(me), me, dppR(me));
        float hmin = fminf(fminf(dppL(hi), hi), dppR(hi));
        m  = med3f(lmax, mid, hmin);
        rs = m + dppL(m) + dppR(m);
    };

    float xa, ya, xb, yb, xc, yc, xd, yd, xe, ye;
    loadrow2(R0 - 1, xa, ya);
    loadrow2(R0,     xb, yb);
    loadrow2(R0 + 1, xc, yc);
    loadrow2(R0 + 2, xd, yd);
    loadrow2(R0 + 3, xe, ye);

    float mx0, mx1, mx2, rx0, rx1, rx2;
    float my0, my1, my2, ry0, ry1, ry2;
    medrow(xa, xb, xc, mx0, rx0); medrow(ya, yb, yc, my0, ry0);
    dopool(xb, xc, yb, yc, phalf);             // pool gray rows (R0, R0+1)
    medrow(xb, xc, xd, mx1, rx1); medrow(yb, yc, yd, my1, ry1);
    medrow(xc, xd, xe, mx2, rx2); medrow(yc, yd, ye, my2, ry2);

    float gx2 = xd, gx3 = xe, gy2 = yd, gy3 = ye;  // gray rows i+2, i+3
    const bool outLane = (lane >= 2) && (lane <= 61) && (c <= Hk - 2);
    float acc = 0.0f;

    for (int i = R0; i < iend; ++i) {
        float nx, ny;
        loadrow2(i + 4, nx, ny);               // prefetch next gray row

        float csx = mx0 + mx1 + mx2;
        float csy = my0 + my1 + my2;
        float Gxx = dppR(csx) - dppL(csx);
        float Gxy = dppR(csy) - dppL(csy);
        float Gyx = rx0 - rx2;
        float Gyy = ry0 - ry2;
        float gI = sqrtf(Gxx * Gxx + Gyx * Gyx) * (1.0f / 3.0f);
        float gR = sqrtf(Gxy * Gxy + Gyy * Gyy) * (1.0f / 3.0f);
        float gmap = (2.0f * gI * gR + C_GMS) / (gI * gI + gR * gR + C_GMS);
        if (outLane) acc += 1.0f - gmap;

        if (((i + 3) & 1) == 1) dopool(gx2, gx3, gy2, gy3, (i + 2) >> 1);

        float mxn, rxn, myn, ryn;
        medrow(gx2, gx3, nx, mxn, rxn);
        medrow(gy2, gy3, ny, myn, ryn);
        mx0 = mx1; mx1 = mx2; mx2 = mxn; rx0 = rx1; rx1 = rx2; rx2 = rxn;
        my0 = my1; my1 = my2; my2 = myn; ry0 = ry1; ry1 = ry2; ry2 = ryn;
        gx2 = gx3; gx3 = nx; gy2 = gy3; gy3 = ny;
    }

    for (int off = 32; off; off >>= 1) acc += __shfl_down(acc, off, 64);
    return acc;
}

// Scale 0: RGB -> gray -> GMS, fused 2x2 pool -> X1/Y1 (256x256 per image).
// On completion: release fence + bump this image's counter.
__device__ __forceinline__ void phase0(
    int u, const float* __restrict__ Ii, const float* __restrict__ Ir,
    float* __restrict__ X1, float* __restrict__ Y1,
    float* __restrict__ P, unsigned int* __restrict__ imgCnt)
{
    const int lane = threadIdx.x & 63;
    const int s  = u % 9;               // strip fastest: halo sharing in L2
    const int t1 = u / 9;
    const int k  = t1 % 64;
    const int b  = t1 / 64;

    const int c  = 60 * s - 1 + lane;
    const int R0 = k * 8;
    const int iend = min(R0 + 8, 510);

    const float* PX = Ii + (size_t)b * 3 * 262144;
    const float* PY = Ir + (size_t)b * 3 * 262144;
    const bool cok = (c >= 0) && (c < 512);

    auto loadrow2 = [&](int r, float& vx, float& vy) {
        vx = 0.0f; vy = 0.0f;
        if (r >= 0 && r < 512 && cok) {
            int o = r * 512 + c;
            vx = (PX[o] + PX[o + 262144] + PX[o + 524288]) * (1.0f / 3.0f);
            vy = (PY[o] + PY[o + 262144] + PY[o + 524288]) * (1.0f / 3.0f);
        }
    };

    const int phalf = R0 >> 1;
    const int pend  = phalf + 4;
    const bool poolLane = ((lane & 1) == 1) && (lane <= 59) && (c + 1 < 512);
    auto dopool = [&](float bx, float cx, float by, float cy, int p) {
        if (p < phalf || p >= pend || p >= 256) return;   // uniform
        float ux = bx + cx, uy = by + cy;
        float hx = ux + dppR(ux);
        float hy = uy + dppR(uy);
        if (poolLane) {
            size_t o = ((size_t)b * 256 + p) * 256 + (c >> 1);
            X1[o] = hx * 0.25f;
            Y1[o] = hy * 0.25f;
        }
    };

    float acc = gms_core(lane, 512, R0, iend, c, phalf, loadrow2, dopool);
    if (lane == 0)
        __hip_atomic_store(&P[u], acc, __ATOMIC_RELAXED, __HIP_MEMORY_SCOPE_AGENT);
    __threadfence();    // agent release: pooled writes visible before counter bump
    if (lane == 0)
        __hip_atomic_fetch_add(&imgCnt[b], 1u, __ATOMIC_RELAXED, __HIP_MEMORY_SCOPE_AGENT);
}

// Scales 1-3, all computed from the 256x256 gray pyramid level X1/Y1 with
// GxG on-the-fly pooling (G = 1,2,4). Waits on the producer counter first.
template<int G>
__device__ __forceinline__ void phaseR(
    int u, const float* __restrict__ X1, const float* __restrict__ Y1,
    int nstrips, int nchunks, float* __restrict__ P,
    unsigned int* __restrict__ imgCnt)
{
    constexpr int Hk = 256 / G;
    const int lane = threadIdx.x & 63;
    const int s  = u % nstrips;
    const int t1 = u / nstrips;
    const int k  = t1 % nchunks;
    const int b  = t1 / nchunks;

    const int c  = 60 * s - 1 + lane;
    const int R0 = k * 8;
    const int iend = min(R0 + 8, Hk - 2);

    const float* Xp = X1 + (size_t)b * 65536;
    const float* Yp = Y1 + (size_t)b * 65536;
    const bool cok = (c >= 0) && (c < Hk);

    // spin until image b's pyramid level is fully written (lane 0 holds the wave)
    if (lane == 0) {
        while (__hip_atomic_load(&imgCnt[b], __ATOMIC_RELAXED,
                                 __HIP_MEMORY_SCOPE_AGENT) < PER_IMG)
            __builtin_amdgcn_s_sleep(2);
    }
    __threadfence();    // agent acquire: invalidate stale lines before reading X1

    auto loadrow2 = [&](int r, float& vx, float& vy) {
        vx = 0.0f; vy = 0.0f;
        if (r >= 0 && r < Hk && cok) {
            if constexpr (G == 1) {
                int o = r * 256 + c;
                vx = Xp[o]; vy = Yp[o];
            } else if constexpr (G == 2) {
                int o = (r * 2) * 256 + c * 2;
                float2 a0 = *(const float2*)(Xp + o);
                float2 a1 = *(const float2*)(Xp + o + 256);
                float2 b0 = *(const float2*)(Yp + o);
                float2 b1 = *(const float2*)(Yp + o + 256);
                vx = ((a0.x + a0.y) + (a1.x + a1.y)) * 0.25f;
                vy = ((b0.x + b0.y) + (b1.x + b1.y)) * 0.25f;
            } else {
                int o = (r * 4) * 256 + c * 4;
                float sx = 0.0f, sy = 0.0f;
                #pragma unroll
                for (int fr = 0; fr < 4; ++fr) {
                    float4 t = *(const float4*)(Xp + o + fr * 256);
                    float4 q = *(const float4*)(Yp + o + fr * 256);
                    sx += (t.x + t.y) + (t.z + t.w);
                    sy += (q.x + q.y) + (q.z + q.w);
                }
                vx = sx * 0.0625f; vy = sy * 0.0625f;
            }
        }
    };
    auto nopool = [&](float, float, float, float, int) {};

    float acc = gms_core(lane, Hk, R0, iend, c, 0, loadrow2, nopool);
    if (lane == 0)
        __hip_atomic_store(&P[u], acc, __ATOMIC_RELAXED, __HIP_MEMORY_SCOPE_AGENT);
}

__global__ __launch_bounds__(256) void msgms_main(
    const float* __restrict__ Ii, const float* __restrict__ Ir,
    float* __restrict__ X1, float* __restrict__ Y1,
    float* __restrict__ P, unsigned int* __restrict__ imgCnt,
    unsigned int* __restrict__ blkCnt, float* __restrict__ out)
{
    const int u = blockIdx.x * 4 + (threadIdx.x >> 6);
    if      (u < N0)           phase0(u, Ii, Ir, X1, Y1, P, imgCnt);
    else if (u < N0 + N1)      phaseR<1>(u - N0,           X1, Y1, 5, 32, P + N0,           imgCnt);
    else if (u < N0 + N1 + N2) phaseR<2>(u - N0 - N1,      X1, Y1, 3, 16, P + N0 + N1,      imgCnt);
    else                       phaseR<4>(u - N0 - N1 - N2, X1, Y1, 2,  8, P + N0 + N1 + N2, imgCnt);

    // ---- last-block finalize (verified R6 pattern) ----
    __shared__ int lastFlag;
    __syncthreads();
    if (threadIdx.x == 0) {
        __threadfence();
        unsigned int old = __hip_atomic_fetch_add(blkCnt, 1u, __ATOMIC_ACQ_REL,
                                                  __HIP_MEMORY_SCOPE_AGENT);
        lastFlag = (old == (unsigned int)(NBLK - 1));
    }
    __syncthreads();
    if (!lastFlag) return;

    __threadfence();
    const int tid = threadIdx.x;
    const double w0 = 1.0 / (4.0 * 16.0 * 510.0 * 510.0);
    const double w1 = 1.0 / (4.0 * 16.0 * 254.0 * 254.0);
    const double w2 = 1.0 / (4.0 * 16.0 * 126.0 * 126.0);
    const double w3 = 1.0 / (4.0 * 16.0 * 62.0 * 62.0);
    double v = 0.0;
    for (int i = tid; i < NTOT; i += 256) {
        float p = __hip_atomic_load(&P[i], __ATOMIC_RELAXED, __HIP_MEMORY_SCOPE_AGENT);
        double w = (i < N0) ? w0 : (i < N0 + N1) ? w1 : (i < N0 + N1 + N2) ? w2 : w3;
        v += (double)p * w;
    }
    for (int off = 32; off; off >>= 1) v += __shfl_down(v, off, 64);
    __shared__ double wsum[4];
    if ((tid & 63) == 0) wsum[tid >> 6] = v;
    __syncthreads();
    if (tid == 0) out[0] = (float)(wsum[0] + wsum[1] + wsum[2] + wsum[3]);
}

extern "C" void kernel_launch(void* const* d_in, const int* in_sizes, int n_in,
                              void* d_out, int out_size, void* d_ws, size_t ws_size,
                              hipStream_t stream) {
    const float* Ii = (const float*)d_in[0];
    const float* Ir = (const float*)d_in[1];
    float* out = (float*)d_out;

    char* ws = (char*)d_ws;
    unsigned int* imgCnt = (unsigned int*)ws;            // 16 counters @ ws+0
    unsigned int* blkCnt = (unsigned int*)(ws + 128);    // 1 counter  @ ws+128
    float* P  = (float*)(ws + 256);                      // NTOT partials
    float* X1 = P + 16384;                               // 16 x 256 x 256 gray
    float* Y1 = X1 + 16 * 256 * 256;

    hipMemsetAsync(ws, 0, 256, stream);                  // zero all counters

    msgms_main<<<NBLK, 256, 0, stream>>>(Ii, Ir, X1, Y1, P, imgCnt, blkCnt, out);
}

// Round 8
// 201.685 us; speedup vs baseline: 5.3157x; 5.3157x over previous
//
#include <hip/hip_runtime.h>

#define C_GMS 0.0026f

// DPP wavefront shifts: full-rate VALU cross-lane, zero LDS latency.
// dppL = value of lane-1 (wf_shr:1, 0x138), lane 0 reads 0 (bound_ctrl)
// dppR = value of lane+1 (wf_shl:1, 0x130), lane 63 reads 0
__device__ __forceinline__ float dppL(float x) {
    return __int_as_float(__builtin_amdgcn_mov_dpp(__float_as_int(x), 0x138, 0xf, 0xf, true));
}
__device__ __forceinline__ float dppR(float x) {
    return __int_as_float(__builtin_amdgcn_mov_dpp(__float_as_int(x), 0x130, 0xf, 0xf, true));
}
__device__ __forceinline__ float med3f(float a, float b, float c) {
    return __builtin_amdgcn_fmed3f(a, b, c);   // exact median-of-3, 1 instr
}

// partial layout: [0,9216) scale0 | [,11776) s1 | [,12544) s2 | [,12800) s3
#define N0 9216
#define N1 2560
#define N2 768
#define N3 256
#define NTOT 12800
#define NBLK_B ((N1 + N2 + N3) / 4)   // 896 blocks in dispatch B

// Rolling GMS core (verified exact R3-R7, absmax=0): one wave = 64-col strip,
// 8 output rows. median9 = med3(max3(col lows), med3(col meds), min3(col highs)).
template<class LoadFn, class PoolFn>
__device__ __forceinline__ float gms_core(int lane, int Hk, int R0, int iend, int c,
                                          int phalf, LoadFn loadrow2, PoolFn dopool)
{
    auto medrow = [&](float ga, float gb, float gc, float& m, float& rs) {
        float lo = fminf(fminf(ga, gb), gc);
        float me = med3f(ga, gb, gc);
        float hi = fmaxf(fmaxf(ga, gb), gc);
        float lmax = fmaxf(fmaxf(dppL(lo), lo), dppR(lo));
        float mid  = med3f(dppL(me), me, dppR(me));
        float hmin = fminf(fminf(dppL(hi), hi), dppR(hi));
        m  = med3f(lmax, mid, hmin);
        rs = m + dppL(m) + dppR(m);
    };

    float xa, ya, xb, yb, xc, yc, xd, yd, xe, ye;
    loadrow2(R0 - 1, xa, ya);
    loadrow2(R0,     xb, yb);
    loadrow2(R0 + 1, xc, yc);
    loadrow2(R0 + 2, xd, yd);
    loadrow2(R0 + 3, xe, ye);

    float mx0, mx1, mx2, rx0, rx1, rx2;
    float my0, my1, my2, ry0, ry1, ry2;
    medrow(xa, xb, xc, mx0, rx0); medrow(ya, yb, yc, my0, ry0);
    dopool(xb, xc, yb, yc, phalf);             // pool gray rows (R0, R0+1)
    medrow(xb, xc, xd, mx1, rx1); medrow(yb, yc, yd, my1, ry1);
    medrow(xc, xd, xe, mx2, rx2); medrow(yc, yd, ye, my2, ry2);

    float gx2 = xd, gx3 = xe, gy2 = yd, gy3 = ye;  // gray rows i+2, i+3
    const bool outLane = (lane >= 2) && (lane <= 61) && (c <= Hk - 2);
    float acc = 0.0f;

    for (int i = R0; i < iend; ++i) {
        float nx, ny;
        loadrow2(i + 4, nx, ny);               // prefetch next gray row

        float csx = mx0 + mx1 + mx2;
        float csy = my0 + my1 + my2;
        float Gxx = dppR(csx) - dppL(csx);
        float Gxy = dppR(csy) - dppL(csy);
        float Gyx = rx0 - rx2;
        float Gyy = ry0 - ry2;
        float gI = sqrtf(Gxx * Gxx + Gyx * Gyx) * (1.0f / 3.0f);
        float gR = sqrtf(Gxy * Gxy + Gyy * Gyy) * (1.0f / 3.0f);
        float gmap = (2.0f * gI * gR + C_GMS) / (gI * gI + gR * gR + C_GMS);
        if (outLane) acc += 1.0f - gmap;

        if (((i + 3) & 1) == 1) dopool(gx2, gx3, gy2, gy3, (i + 2) >> 1);

        float mxn, rxn, myn, ryn;
        medrow(gx2, gx3, nx, mxn, rxn);
        medrow(gy2, gy3, ny, myn, ryn);
        mx0 = mx1; mx1 = mx2; mx2 = mxn; rx0 = rx1; rx1 = rx2; rx2 = rxn;
        my0 = my1; my1 = my2; my2 = myn; ry0 = ry1; ry1 = ry2; ry2 = ryn;
        gx2 = gx3; gx3 = nx; gy2 = gy3; gy3 = ny;
    }

    for (int off = 32; off; off >>= 1) acc += __shfl_down(acc, off, 64);
    return acc;
}

// Dispatch A: scale0 from RGB + fused 2x2 pool -> X1/Y1. R5's proven kernel.
__global__ __launch_bounds__(256) void msgms_scale0(
    const float* __restrict__ Ii, const float* __restrict__ Ir,
    float* __restrict__ X1, float* __restrict__ Y1, float* __restrict__ P)
{
    const int lane = threadIdx.x & 63;
    const int u = blockIdx.x * 4 + (threadIdx.x >> 6);
    const int s  = u % 9;               // strip fastest: halo sharing in L2
    const int t1 = u / 9;
    const int k  = t1 % 64;
    const int b  = t1 / 64;

    const int c  = 60 * s - 1 + lane;
    const int R0 = k * 8;
    const int iend = min(R0 + 8, 510);

    const float* PX = Ii + (size_t)b * 3 * 262144;
    const float* PY = Ir + (size_t)b * 3 * 262144;
    const bool cok = (c >= 0) && (c < 512);

    auto loadrow2 = [&](int r, float& vx, float& vy) {
        vx = 0.0f; vy = 0.0f;
        if (r >= 0 && r < 512 && cok) {
            int o = r * 512 + c;
            vx = (PX[o] + PX[o + 262144] + PX[o + 524288]) * (1.0f / 3.0f);
            vy = (PY[o] + PY[o + 262144] + PY[o + 524288]) * (1.0f / 3.0f);
        }
    };

    const int phalf = R0 >> 1;
    const int pend  = phalf + 4;
    const bool poolLane = ((lane & 1) == 1) && (lane <= 59) && (c + 1 < 512);
    auto dopool = [&](float bx, float cx, float by, float cy, int p) {
        if (p < phalf || p >= pend || p >= 256) return;   // uniform
        float ux = bx + cx, uy = by + cy;
        float hx = ux + dppR(ux);
        float hy = uy + dppR(uy);
        if (poolLane) {
            size_t o = ((size_t)b * 256 + p) * 256 + (c >> 1);
            X1[o] = hx * 0.25f;
            Y1[o] = hy * 0.25f;
        }
    };

    float acc = gms_core(lane, 512, R0, iend, c, phalf, loadrow2, dopool);
    if (lane == 0) P[u] = acc;
}

// Dispatch B: scales 1-3 from X1/Y1 with GxG on-the-fly pooling (G=1,2,4),
// then last-block finalize over ALL partials (dispatch boundary made
// dispatch A's writes coherent; no device fences needed in the hot path).
template<int G>
__device__ __forceinline__ void phaseR(
    int u, const float* __restrict__ X1, const float* __restrict__ Y1,
    int nstrips, int nchunks, float* __restrict__ P)
{
    constexpr int Hk = 256 / G;
    const int lane = threadIdx.x & 63;
    const int s  = u % nstrips;
    const int t1 = u / nstrips;
    const int k  = t1 % nchunks;
    const int b  = t1 / nchunks;

    const int c  = 60 * s - 1 + lane;
    const int R0 = k * 8;
    const int iend = min(R0 + 8, Hk - 2);

    const float* Xp = X1 + (size_t)b * 65536;
    const float* Yp = Y1 + (size_t)b * 65536;
    const bool cok = (c >= 0) && (c < Hk);

    auto loadrow2 = [&](int r, float& vx, float& vy) {
        vx = 0.0f; vy = 0.0f;
        if (r >= 0 && r < Hk && cok) {
            if constexpr (G == 1) {
                int o = r * 256 + c;
                vx = Xp[o]; vy = Yp[o];
            } else if constexpr (G == 2) {
                int o = (r * 2) * 256 + c * 2;
                float2 a0 = *(const float2*)(Xp + o);
                float2 a1 = *(const float2*)(Xp + o + 256);
                float2 b0 = *(const float2*)(Yp + o);
                float2 b1 = *(const float2*)(Yp + o + 256);
                vx = ((a0.x + a0.y) + (a1.x + a1.y)) * 0.25f;
                vy = ((b0.x + b0.y) + (b1.x + b1.y)) * 0.25f;
            } else {
                int o = (r * 4) * 256 + c * 4;
                float sx = 0.0f, sy = 0.0f;
                #pragma unroll
                for (int fr = 0; fr < 4; ++fr) {
                    float4 t = *(const float4*)(Xp + o + fr * 256);
                    float4 q = *(const float4*)(Yp + o + fr * 256);
                    sx += (t.x + t.y) + (t.z + t.w);
                    sy += (q.x + q.y) + (q.z + q.w);
                }
                vx = sx * 0.0625f; vy = sy * 0.0625f;
            }
        }
    };
    auto nopool = [&](float, float, float, float, int) {};

    float acc = gms_core(lane, Hk, R0, iend, c, 0, loadrow2, nopool);
    if (lane == 0) P[u] = acc;
}

__global__ __launch_bounds__(256) void msgms_rest(
    const float* __restrict__ X1, const float* __restrict__ Y1,
    float* __restrict__ P, unsigned int* __restrict__ blkCnt,
    float* __restrict__ out)
{
    const int u = blockIdx.x * 4 + (threadIdx.x >> 6);
    if      (u < N1)      phaseR<1>(u,           X1, Y1, 5, 32, P + N0);
    else if (u < N1 + N2) phaseR<2>(u - N1,      X1, Y1, 3, 16, P + N0 + N1);
    else                  phaseR<4>(u - N1 - N2, X1, Y1, 2,  8, P + N0 + N1 + N2);

    // ---- last-block finalize (verified R6 pattern) ----
    __shared__ int lastFlag;
    __syncthreads();
    if (threadIdx.x == 0) {
        __threadfence();
        unsigned int old = __hip_atomic_fetch_add(blkCnt, 1u, __ATOMIC_ACQ_REL,
                                                  __HIP_MEMORY_SCOPE_AGENT);
        lastFlag = (old == (unsigned int)(NBLK_B - 1));
    }
    __syncthreads();
    if (!lastFlag) return;

    __threadfence();
    const int tid = threadIdx.x;
    const double w0 = 1.0 / (4.0 * 16.0 * 510.0 * 510.0);
    const double w1 = 1.0 / (4.0 * 16.0 * 254.0 * 254.0);
    const double w2 = 1.0 / (4.0 * 16.0 * 126.0 * 126.0);
    const double w3 = 1.0 / (4.0 * 16.0 * 62.0 * 62.0);
    double v = 0.0;
    for (int i = tid; i < NTOT; i += 256) {
        float p = __hip_atomic_load(&P[i], __ATOMIC_RELAXED, __HIP_MEMORY_SCOPE_AGENT);
        double w = (i < N0) ? w0 : (i < N0 + N1) ? w1 : (i < N0 + N1 + N2) ? w2 : w3;
        v += (double)p * w;
    }
    for (int off = 32; off; off >>= 1) v += __shfl_down(v, off, 64);
    __shared__ double wsum[4];
    if ((tid & 63) == 0) wsum[tid >> 6] = v;
    __syncthreads();
    if (tid == 0) out[0] = (float)(wsum[0] + wsum[1] + wsum[2] + wsum[3]);
}

extern "C" void kernel_launch(void* const* d_in, const int* in_sizes, int n_in,
                              void* d_out, int out_size, void* d_ws, size_t ws_size,
                              hipStream_t stream) {
    const float* Ii = (const float*)d_in[0];
    const float* Ir = (const float*)d_in[1];
    float* out = (float*)d_out;

    char* ws = (char*)d_ws;
    unsigned int* blkCnt = (unsigned int*)ws;            // 4 B used, 256 B reserved
    float* P  = (float*)(ws + 256);                      // NTOT partials
    float* X1 = P + 16384;                               // 16 x 256 x 256 gray
    float* Y1 = X1 + 16 * 256 * 256;

    hipMemsetAsync(ws, 0, 256, stream);                  // zero block counter

    msgms_scale0<<<N0 / 4, 256, 0, stream>>>(Ii, Ir, X1, Y1, P);
    msgms_rest<<<NBLK_B, 256, 0, stream>>>(X1, Y1, P, blkCnt, out);
}

// Round 9
// 150.028 us; speedup vs baseline: 7.1460x; 1.3443x over previous
//
#include <hip/hip_runtime.h>

#define C_GMS 0.0026f

// DPP wavefront shifts: full-rate VALU cross-lane, zero LDS latency.
// dppL = value of lane-1 (wf_shr:1, 0x138), lane 0 reads 0 (bound_ctrl)
// dppR = value of lane+1 (wf_shl:1, 0x130), lane 63 reads 0
__device__ __forceinline__ float dppL(float x) {
    return __int_as_float(__builtin_amdgcn_mov_dpp(__float_as_int(x), 0x138, 0xf, 0xf, true));
}
__device__ __forceinline__ float dppR(float x) {
    return __int_as_float(__builtin_amdgcn_mov_dpp(__float_as_int(x), 0x130, 0xf, 0xf, true));
}
__device__ __forceinline__ float med3f(float a, float b, float c) {
    return __builtin_amdgcn_fmed3f(a, b, c);   // exact median-of-3, 1 instr
}

// partial layout: [0,4608) scale0 | [,7168) s1 | [,7936) s2 | [,8192) s3
#define N0 4608
#define N1 2560
#define N2 768
#define N3 256
#define NTOT 8192

// Rolling GMS core (verified exact R3-R8, absmax=0): one wave = 64-col strip,
// rolls down output rows. median9 = med3(max3(lo), med3(me), min3(hi)).
template<class LoadFn, class PoolFn>
__device__ __forceinline__ float gms_core(int lane, int Hk, int R0, int iend, int c,
                                          int phalf, LoadFn loadrow2, PoolFn dopool)
{
    auto medrow = [&](float ga, float gb, float gc, float& m, float& rs) {
        float lo = fminf(fminf(ga, gb), gc);
        float me = med3f(ga, gb, gc);
        float hi = fmaxf(fmaxf(ga, gb), gc);
        float lmax = fmaxf(fmaxf(dppL(lo), lo), dppR(lo));
        float mid  = med3f(dppL(me), me, dppR(me));
        float hmin = fminf(fminf(dppL(hi), hi), dppR(hi));
        m  = med3f(lmax, mid, hmin);
        rs = m + dppL(m) + dppR(m);
    };

    float xa, ya, xb, yb, xc, yc, xd, yd, xe, ye;
    loadrow2(R0 - 1, xa, ya);
    loadrow2(R0,     xb, yb);
    loadrow2(R0 + 1, xc, yc);
    loadrow2(R0 + 2, xd, yd);
    loadrow2(R0 + 3, xe, ye);

    float mx0, mx1, mx2, rx0, rx1, rx2;
    float my0, my1, my2, ry0, ry1, ry2;
    medrow(xa, xb, xc, mx0, rx0); medrow(ya, yb, yc, my0, ry0);
    dopool(xb, xc, yb, yc, phalf);             // pool gray rows (R0, R0+1)
    medrow(xb, xc, xd, mx1, rx1); medrow(yb, yc, yd, my1, ry1);
    medrow(xc, xd, xe, mx2, rx2); medrow(yc, yd, ye, my2, ry2);

    float gx2 = xd, gx3 = xe, gy2 = yd, gy3 = ye;  // gray rows i+2, i+3
    const bool outLane = (lane >= 2) && (lane <= 61) && (c <= Hk - 2);
    float acc = 0.0f;

    for (int i = R0; i < iend; ++i) {
        float nx, ny;
        loadrow2(i + 4, nx, ny);               // prefetch next gray row

        float csx = mx0 + mx1 + mx2;
        float csy = my0 + my1 + my2;
        float Gxx = dppR(csx) - dppL(csx);
        float Gxy = dppR(csy) - dppL(csy);
        float Gyx = rx0 - rx2;
        float Gyy = ry0 - ry2;
        float gI = sqrtf(Gxx * Gxx + Gyx * Gyx) * (1.0f / 3.0f);
        float gR = sqrtf(Gxy * Gxy + Gyy * Gyy) * (1.0f / 3.0f);
        float gmap = (2.0f * gI * gR + C_GMS) / (gI * gI + gR * gR + C_GMS);
        if (outLane) acc += 1.0f - gmap;

        if (((i + 3) & 1) == 1) dopool(gx2, gx3, gy2, gy3, (i + 2) >> 1);

        float mxn, rxn, myn, ryn;
        medrow(gx2, gx3, nx, mxn, rxn);
        medrow(gy2, gy3, ny, myn, ryn);
        mx0 = mx1; mx1 = mx2; mx2 = mxn; rx0 = rx1; rx1 = rx2; rx2 = rxn;
        my0 = my1; my1 = my2; my2 = myn; ry0 = ry1; ry1 = ry2; ry2 = ryn;
        gx2 = gx3; gx3 = nx; gy2 = gy3; gy3 = ny;
    }

    for (int off = 32; off; off >>= 1) acc += __shfl_down(acc, off, 64);
    return acc;
}

// Dispatch A: scale0 from RGB + fused 2x2 pool -> X1/Y1. RC=16 (halved
// warmup & halo re-reads vs R5's RC=8). Plain stores only.
__global__ __launch_bounds__(256) void msgms_scale0(
    const float* __restrict__ Ii, const float* __restrict__ Ir,
    float* __restrict__ X1, float* __restrict__ Y1, float* __restrict__ P)
{
    const int lane = threadIdx.x & 63;
    const int u = blockIdx.x * 4 + (threadIdx.x >> 6);
    const int s  = u % 9;               // strip fastest: halo sharing in L2
    const int t1 = u / 9;
    const int k  = t1 % 32;             // 32 chunks of 16 rows
    const int b  = t1 / 32;

    const int c  = 60 * s - 1 + lane;
    const int R0 = k * 16;
    const int iend = min(R0 + 16, 510);

    const float* PX = Ii + (size_t)b * 3 * 262144;
    const float* PY = Ir + (size_t)b * 3 * 262144;
    const bool cok = (c >= 0) && (c < 512);

    auto loadrow2 = [&](int r, float& vx, float& vy) {
        vx = 0.0f; vy = 0.0f;
        if (r >= 0 && r < 512 && cok) {
            int o = r * 512 + c;
            vx = (PX[o] + PX[o + 262144] + PX[o + 524288]) * (1.0f / 3.0f);
            vy = (PY[o] + PY[o + 262144] + PY[o + 524288]) * (1.0f / 3.0f);
        }
    };

    const int phalf = R0 >> 1;
    const int pend  = min(phalf + 8, 256);
    const bool poolLane = ((lane & 1) == 1) && (lane <= 59) && (c + 1 < 512);
    auto dopool = [&](float bx, float cx, float by, float cy, int p) {
        if (p < phalf || p >= pend) return;   // uniform
        float ux = bx + cx, uy = by + cy;
        float hx = ux + dppR(ux);
        float hy = uy + dppR(uy);
        if (poolLane) {
            size_t o = ((size_t)b * 256 + p) * 256 + (c >> 1);
            X1[o] = hx * 0.25f;
            Y1[o] = hy * 0.25f;
        }
    };

    float acc = gms_core(lane, 512, R0, iend, c, phalf, loadrow2, dopool);
    if (lane == 0) P[u] = acc;
}

// Dispatch B: scales 1-3 from X1/Y1 with GxG on-the-fly pooling (G=1,2,4).
// Plain stores; dispatch boundary provides coherence. ZERO fences/atomics.
template<int G>
__device__ __forceinline__ void phaseR(
    int u, const float* __restrict__ X1, const float* __restrict__ Y1,
    int nstrips, int nchunks, float* __restrict__ P)
{
    constexpr int Hk = 256 / G;
    const int lane = threadIdx.x & 63;
    const int s  = u % nstrips;
    const int t1 = u / nstrips;
    const int k  = t1 % nchunks;
    const int b  = t1 / nchunks;

    const int c  = 60 * s - 1 + lane;
    const int R0 = k * 8;
    const int iend = min(R0 + 8, Hk - 2);

    const float* Xp = X1 + (size_t)b * 65536;
    const float* Yp = Y1 + (size_t)b * 65536;
    const bool cok = (c >= 0) && (c < Hk);

    auto loadrow2 = [&](int r, float& vx, float& vy) {
        vx = 0.0f; vy = 0.0f;
        if (r >= 0 && r < Hk && cok) {
            if constexpr (G == 1) {
                int o = r * 256 + c;
                vx = Xp[o]; vy = Yp[o];
            } else if constexpr (G == 2) {
                int o = (r * 2) * 256 + c * 2;
                float2 a0 = *(const float2*)(Xp + o);
                float2 a1 = *(const float2*)(Xp + o + 256);
                float2 b0 = *(const float2*)(Yp + o);
                float2 b1 = *(const float2*)(Yp + o + 256);
                vx = ((a0.x + a0.y) + (a1.x + a1.y)) * 0.25f;
                vy = ((b0.x + b0.y) + (b1.x + b1.y)) * 0.25f;
            } else {
                int o = (r * 4) * 256 + c * 4;
                float sx = 0.0f, sy = 0.0f;
                #pragma unroll
                for (int fr = 0; fr < 4; ++fr) {
                    float4 t = *(const float4*)(Xp + o + fr * 256);
                    float4 q = *(const float4*)(Yp + o + fr * 256);
                    sx += (t.x + t.y) + (t.z + t.w);
                    sy += (q.x + q.y) + (q.z + q.w);
                }
                vx = sx * 0.0625f; vy = sy * 0.0625f;
            }
        }
    };
    auto nopool = [&](float, float, float, float, int) {};

    float acc = gms_core(lane, Hk, R0, iend, c, 0, loadrow2, nopool);
    if (lane == 0) P[u] = acc;
}

__global__ __launch_bounds__(256) void msgms_rest(
    const float* __restrict__ X1, const float* __restrict__ Y1,
    float* __restrict__ P)
{
    const int u = blockIdx.x * 4 + (threadIdx.x >> 6);
    if      (u < N1)      phaseR<1>(u,           X1, Y1, 5, 32, P + N0);
    else if (u < N1 + N2) phaseR<2>(u - N1,      X1, Y1, 3, 16, P + N0 + N1);
    else                  phaseR<4>(u - N1 - N2, X1, Y1, 2,  8, P + N0 + N1 + N2);
}

// Dispatch C: one block, weighted sum of all partials. Plain loads.
__global__ __launch_bounds__(256) void msgms_final(
    const float* __restrict__ P, float* __restrict__ out)
{
    const int tid = threadIdx.x;
    const double w0 = 1.0 / (4.0 * 16.0 * 510.0 * 510.0);
    const double w1 = 1.0 / (4.0 * 16.0 * 254.0 * 254.0);
    const double w2 = 1.0 / (4.0 * 16.0 * 126.0 * 126.0);
    const double w3 = 1.0 / (4.0 * 16.0 * 62.0 * 62.0);
    double v = 0.0;
    for (int i = tid; i < NTOT; i += 256) {
        double w = (i < N0) ? w0 : (i < N0 + N1) ? w1 : (i < N0 + N1 + N2) ? w2 : w3;
        v += (double)P[i] * w;
    }
    for (int off = 32; off; off >>= 1) v += __shfl_down(v, off, 64);
    __shared__ double wsum[4];
    if ((tid & 63) == 0) wsum[tid >> 6] = v;
    __syncthreads();
    if (tid == 0) out[0] = (float)(wsum[0] + wsum[1] + wsum[2] + wsum[3]);
}

extern "C" void kernel_launch(void* const* d_in, const int* in_sizes, int n_in,
                              void* d_out, int out_size, void* d_ws, size_t ws_size,
                              hipStream_t stream) {
    const float* Ii = (const float*)d_in[0];
    const float* Ir = (const float*)d_in[1];
    float* out = (float*)d_out;

    char* ws = (char*)d_ws;
    float* P  = (float*)ws;                              // NTOT partials
    float* X1 = P + NTOT;                                // 16 x 256 x 256 gray
    float* Y1 = X1 + 16 * 256 * 256;

    msgms_scale0<<<N0 / 4, 256, 0, stream>>>(Ii, Ir, X1, Y1, P);
    msgms_rest<<<(N1 + N2 + N3) / 4, 256, 0, stream>>>(X1, Y1, P);
    msgms_final<<<1, 256, 0, stream>>>(P, out);
}